// Round 1
// baseline (418.631 us; speedup 1.0000x reference)
//
#include <hip/hip_runtime.h>
#include <hip/hip_bf16.h>

#define RES 320
#define CELLS (RES * RES)

// ---------------------------------------------------------------------------
// Wave-level run-segmented atomic add: lanes with equal `key` in a contiguous
// run combine their `val`s; only the tail lane of each run issues the atomic.
// key < 0 => skip atomic. Handles the degenerate trajectory points (thousands
// of points scattering to the same cell) without serializing at L2.
// ---------------------------------------------------------------------------
__device__ __forceinline__ void seg_atomic_add(float* base, int key, float val, int lane) {
    int prev = __shfl_up(key, 1);
    bool head = (lane == 0) || (prev != key);
    unsigned long long hb = __ballot(head);
    unsigned long long below = (lane == 63) ? hb : (hb & ((1ULL << (lane + 1)) - 1ULL));
    int run_start = 63 - __clzll(below);   // hb bit 0 always set (lane 0 is head)
#pragma unroll
    for (int d = 1; d < 64; d <<= 1) {
        float o = __shfl_up(val, d);
        if (lane - d >= run_start) val += o;
    }
    bool tail = (lane == 63) || ((hb >> (lane + 1)) & 1ULL);
    if (tail && key >= 0) atomicAdd(base + key, val);
}

// ---------------------------------------------------------------------------
// Build the 9-point stencil weights M9 (SoA: M9[slot*CELLS + cell]) from the
// trajectory. For each point: 4 gather corners (i) x 4 scatter corners (j),
// weight product w_j*w_i accumulates at target cell_j, offset slot (di-dj).
// ---------------------------------------------------------------------------
__global__ __launch_bounds__(256) void build_m9(const float* __restrict__ traj, int P,
                                                float* __restrict__ M9) {
    int p = blockIdx.x * 256 + threadIdx.x;
    int lane = threadIdx.x & 63;
    bool active = (p < P);
    int pp = active ? p : (P > 0 ? P - 1 : 0);
    float t0 = traj[2 * pp];
    float t1 = traj[2 * pp + 1];
    float gx = t0 * (2.0f / RES);
    float gy = t1 * (2.0f / RES);
    float x = ((gx + 1.0f) * RES - 1.0f) * 0.5f;
    float y = ((gy + 1.0f) * RES - 1.0f) * 0.5f;
    float x0f = floorf(x), y0f = floorf(y);
    float fx = x - x0f, fy = y - y0f;
    int x0 = (int)x0f, y0 = (int)y0f;

    const int ox[4] = {0, 1, 0, 1};
    const int oy[4] = {0, 0, 1, 1};
    float w[4] = {(1.f - fx) * (1.f - fy), fx * (1.f - fy), (1.f - fx) * fy, fx * fy};
    int cellv[4];
    bool v[4];
#pragma unroll
    for (int k = 0; k < 4; k++) {
        int cx = x0 + ox[k], cy = y0 + oy[k];
        v[k] = active && (cx >= 0) && (cx < RES) && (cy >= 0) && (cy < RES);
        cellv[k] = cy * RES + cx;
    }
#pragma unroll
    for (int j = 0; j < 4; j++) {      // scatter (target) corner
#pragma unroll
        for (int i = 0; i < 4; i++) {  // gather (source) corner
            int slot = (oy[i] - oy[j] + 1) * 3 + (ox[i] - ox[j] + 1);
            int key = (v[i] && v[j]) ? cellv[j] : -1;
            seg_atomic_add(M9 + (size_t)slot * CELLS, key, w[j] * w[i], lane);
        }
    }
}

// ---------------------------------------------------------------------------
// F[u,y] = (-1)^u (-1)^y exp(+2*pi*i*u*y/RES)  — folds ifftshift/fftshift
// (roll by N/2, N even) into the inverse-DFT matrix. img = F * grid * F.
// ---------------------------------------------------------------------------
__global__ __launch_bounds__(256) void make_F(float2* __restrict__ F) {
    int idx = blockIdx.x * 256 + threadIdx.x;
    if (idx >= CELLS) return;
    int u = idx / RES, y = idx % RES;
    int r = (u * y) % RES;
    float s, c;
    sincospif((float)r * (2.0f / RES), &s, &c);
    float sign = ((u + y) & 1) ? -1.0f : 1.0f;
    F[idx] = make_float2(sign * c, sign * s);
}

// ---------------------------------------------------------------------------
// Apply the 9-point stencil: grid[b,cell] = sum_s M9[s,cell] * c[b, nb(s)].
// OOB neighbors are clamped; their weight is exactly 0 by construction.
// ---------------------------------------------------------------------------
__global__ __launch_bounds__(256) void stencil(const float2* __restrict__ ksp,
                                               const float* __restrict__ M9,
                                               float2* __restrict__ grid, int B) {
    int cell = blockIdx.x * 256 + threadIdx.x;
    if (cell >= CELLS) return;
    int cy = cell / RES, cx = cell % RES;
    float w[9];
#pragma unroll
    for (int s = 0; s < 9; s++) w[s] = M9[(size_t)s * CELLS + cell];
    int nidx[9];
#pragma unroll
    for (int dy = -1; dy <= 1; dy++) {
#pragma unroll
        for (int dx = -1; dx <= 1; dx++) {
            int ny = min(max(cy + dy, 0), RES - 1);
            int nx = min(max(cx + dx, 0), RES - 1);
            nidx[(dy + 1) * 3 + (dx + 1)] = ny * RES + nx;
        }
    }
    for (int b = 0; b < B; b++) {
        const float2* cb = ksp + (size_t)b * CELLS;
        float re = 0.f, im = 0.f;
#pragma unroll
        for (int s = 0; s < 9; s++) {
            float2 vv = cb[nidx[s]];
            re = fmaf(w[s], vv.x, re);
            im = fmaf(w[s], vv.y, im);
        }
        grid[(size_t)b * CELLS + cell] = make_float2(re, im);
    }
}

// ---------------------------------------------------------------------------
// Complex GEMM 1: T[b][m][n] = sum_k F[m][k] * G[b][k][n]   (320x320x320)
// 32x32 tile, 256 threads, 4 outputs/thread.
// ---------------------------------------------------------------------------
__global__ __launch_bounds__(256) void cgemm_FG(const float2* __restrict__ F,
                                                const float2* __restrict__ G,
                                                float2* __restrict__ T) {
    __shared__ float2 As[32][32];
    __shared__ float2 Bs[32][33];
    int b = blockIdx.z;
    int m0 = blockIdx.y * 32, n0 = blockIdx.x * 32;
    const float2* Bb = G + (size_t)b * CELLS;
    int t = threadIdx.x, tx = t & 31, ty = t >> 5;  // ty in 0..7
    float2 acc[4];
#pragma unroll
    for (int i = 0; i < 4; i++) acc[i] = make_float2(0.f, 0.f);

    for (int k0 = 0; k0 < RES; k0 += 32) {
#pragma unroll
        for (int i = 0; i < 4; i++) {
            int row = ty + 8 * i;
            As[row][tx] = F[(size_t)(m0 + row) * RES + k0 + tx];
            Bs[row][tx] = Bb[(size_t)(k0 + row) * RES + n0 + tx];
        }
        __syncthreads();
#pragma unroll 8
        for (int k = 0; k < 32; k++) {
            float2 bv = Bs[k][tx];
#pragma unroll
            for (int i = 0; i < 4; i++) {
                float2 av = As[ty + 8 * i][k];
                acc[i].x = fmaf(av.x, bv.x, fmaf(-av.y, bv.y, acc[i].x));
                acc[i].y = fmaf(av.x, bv.y, fmaf(av.y, bv.x, acc[i].y));
            }
        }
        __syncthreads();
    }
#pragma unroll
    for (int i = 0; i < 4; i++)
        T[(size_t)b * CELLS + (size_t)(m0 + ty + 8 * i) * RES + n0 + tx] = acc[i];
}

// ---------------------------------------------------------------------------
// Complex GEMM 2: img[b][m][n] = sum_k T[b][m][k] * F[k][n]; write planar
// re/im into d_out layout (b, 1, 2, H, W).
// ---------------------------------------------------------------------------
__global__ __launch_bounds__(256) void cgemm_TF(const float2* __restrict__ T,
                                                const float2* __restrict__ F,
                                                float* __restrict__ out) {
    __shared__ float2 As[32][32];
    __shared__ float2 Bs[32][33];
    int b = blockIdx.z;
    int m0 = blockIdx.y * 32, n0 = blockIdx.x * 32;
    const float2* Ab = T + (size_t)b * CELLS;
    int t = threadIdx.x, tx = t & 31, ty = t >> 5;
    float2 acc[4];
#pragma unroll
    for (int i = 0; i < 4; i++) acc[i] = make_float2(0.f, 0.f);

    for (int k0 = 0; k0 < RES; k0 += 32) {
#pragma unroll
        for (int i = 0; i < 4; i++) {
            int row = ty + 8 * i;
            As[row][tx] = Ab[(size_t)(m0 + row) * RES + k0 + tx];
            Bs[row][tx] = F[(size_t)(k0 + row) * RES + n0 + tx];
        }
        __syncthreads();
#pragma unroll 8
        for (int k = 0; k < 32; k++) {
            float2 bv = Bs[k][tx];
#pragma unroll
            for (int i = 0; i < 4; i++) {
                float2 av = As[ty + 8 * i][k];
                acc[i].x = fmaf(av.x, bv.x, fmaf(-av.y, bv.y, acc[i].x));
                acc[i].y = fmaf(av.x, bv.y, fmaf(av.y, bv.x, acc[i].y));
            }
        }
        __syncthreads();
    }
    float* out_re = out + (size_t)(b * 2 + 0) * CELLS;
    float* out_im = out + (size_t)(b * 2 + 1) * CELLS;
#pragma unroll
    for (int i = 0; i < 4; i++) {
        size_t o = (size_t)(m0 + ty + 8 * i) * RES + n0 + tx;
        out_re[o] = acc[i].x;
        out_im[o] = acc[i].y;
    }
}

extern "C" void kernel_launch(void* const* d_in, const int* in_sizes, int n_in,
                              void* d_out, int out_size, void* d_ws, size_t ws_size,
                              hipStream_t stream) {
    const float* ksp = (const float*)d_in[0];
    const float* traj = (const float*)d_in[1];
    int P = in_sizes[1] / 2;             // 102400 trajectory points
    int B = in_sizes[0] / (CELLS * 2);   // 32 batches

    // Workspace layout (floats):
    //   M9   : 9*CELLS                      (3.7 MB)
    //   F    : 2*CELLS (float2)             (0.8 MB)
    //   grid : B*CELLS float2               (26.2 MB)
    //   T    : B*CELLS float2               (26.2 MB)
    float* ws = (float*)d_ws;
    float* M9 = ws;
    float2* F = (float2*)(ws + (size_t)9 * CELLS);
    float2* grid = (float2*)(ws + (size_t)11 * CELLS);
    float2* T = grid + (size_t)B * CELLS;

    hipMemsetAsync(M9, 0, (size_t)9 * CELLS * sizeof(float), stream);
    build_m9<<<(P + 255) / 256, 256, 0, stream>>>(traj, P, M9);
    make_F<<<(CELLS + 255) / 256, 256, 0, stream>>>(F);
    stencil<<<(CELLS + 255) / 256, 256, 0, stream>>>((const float2*)ksp, M9, grid, B);

    dim3 g(RES / 32, RES / 32, B);
    cgemm_FG<<<g, 256, 0, stream>>>(F, grid, T);
    cgemm_TF<<<g, 256, 0, stream>>>(T, F, (float*)d_out);
}

// Round 2
// 202.847 us; speedup vs baseline: 2.0638x; 2.0638x over previous
//
#include <hip/hip_runtime.h>

#define RES 320
#define CELLS (RES * RES)
#define MDIM 640      // 2*RES (Re/Im stacked)
#define NCOLS 10240   // 32 batches * RES

typedef __attribute__((ext_vector_type(8))) short short8;
typedef __attribute__((ext_vector_type(4))) float f32x4;

// round-to-nearest-even f32 -> bf16 bits (all values finite here)
static __device__ __forceinline__ short f2bf(float f) {
    unsigned u = __builtin_bit_cast(unsigned, f);
    unsigned r = (u + 0x7fffu + ((u >> 16) & 1u)) >> 16;
    return (short)r;
}

#define GLD16(g, l) __builtin_amdgcn_global_load_lds(                        \
    (const __attribute__((address_space(1))) void*)(g),                      \
    (__attribute__((address_space(3))) void*)(l), 16, 0, 0)

// ---------------------------------------------------------------------------
// Wave-level run-segmented atomic add (handles the 21769 degenerate points
// that all target cell 0 without serializing atomics).
// ---------------------------------------------------------------------------
__device__ __forceinline__ void seg_atomic_add(float* base, int key, float val, int lane) {
    int prev = __shfl_up(key, 1);
    bool head = (lane == 0) || (prev != key);
    unsigned long long hb = __ballot(head);
    unsigned long long below = (lane == 63) ? hb : (hb & ((1ULL << (lane + 1)) - 1ULL));
    int run_start = 63 - __clzll(below);
#pragma unroll
    for (int d = 1; d < 64; d <<= 1) {
        float o = __shfl_up(val, d);
        if (lane - d >= run_start) val += o;
    }
    bool tail = (lane == 63) || ((hb >> (lane + 1)) & 1ULL);
    if (tail && key >= 0) atomicAdd(base + key, val);
}

// ---------------------------------------------------------------------------
// Build 9-point stencil weights M9 (SoA: M9[slot*CELLS + cell]).
// ---------------------------------------------------------------------------
__global__ __launch_bounds__(256) void build_m9(const float* __restrict__ traj, int P,
                                                float* __restrict__ M9) {
    int p = blockIdx.x * 256 + threadIdx.x;
    int lane = threadIdx.x & 63;
    bool active = (p < P);
    int pp = active ? p : (P > 0 ? P - 1 : 0);
    float t0 = traj[2 * pp];
    float t1 = traj[2 * pp + 1];
    float x = ((t0 * (2.0f / RES) + 1.0f) * RES - 1.0f) * 0.5f;
    float y = ((t1 * (2.0f / RES) + 1.0f) * RES - 1.0f) * 0.5f;
    float x0f = floorf(x), y0f = floorf(y);
    float fx = x - x0f, fy = y - y0f;
    int x0 = (int)x0f, y0 = (int)y0f;

    const int ox[4] = {0, 1, 0, 1};
    const int oy[4] = {0, 0, 1, 1};
    float w[4] = {(1.f - fx) * (1.f - fy), fx * (1.f - fy), (1.f - fx) * fy, fx * fy};
    int cellv[4];
    bool v[4];
#pragma unroll
    for (int k = 0; k < 4; k++) {
        int cx = x0 + ox[k], cy = y0 + oy[k];
        v[k] = active && (cx >= 0) && (cx < RES) && (cy >= 0) && (cy < RES);
        cellv[k] = cy * RES + cx;
    }
#pragma unroll
    for (int j = 0; j < 4; j++) {
#pragma unroll
        for (int i = 0; i < 4; i++) {
            int slot = (oy[i] - oy[j] + 1) * 3 + (ox[i] - ox[j] + 1);
            int key = (v[i] && v[j]) ? cellv[j] : -1;
            seg_atomic_add(M9 + (size_t)slot * CELLS, key, w[j] * w[i], lane);
        }
    }
}

// ---------------------------------------------------------------------------
// F1[m'][y'] bf16, 640x640: block matrix [[Fr,-Fi],[Fi,Fr]] of
// F[u,y] = (-1)^(u+y) exp(+2*pi*i*u*y/RES). Serves as stage-1 A (row-major
// [m][k]) and stage-2 B ([n][k]) operand (F symmetric).
// ---------------------------------------------------------------------------
__global__ __launch_bounds__(256) void make_F1(short* __restrict__ F1) {
    int idx = blockIdx.x * 256 + threadIdx.x;
    if (idx >= MDIM * MDIM) return;
    int mp = idx / MDIM, yp = idx % MDIM;
    int cm = mp >= RES, cy = yp >= RES;
    int m = mp - RES * cm, y = yp - RES * cy;
    int r = (m * y) % RES;
    float s, c;
    sincospif((float)r * (2.0f / RES), &s, &c);
    float sign = ((m + y) & 1) ? -1.0f : 1.0f;
    float fr = sign * c, fi = sign * s;
    float val = (cm == 0) ? (cy == 0 ? fr : -fi) : (cy == 0 ? fi : fr);
    F1[idx] = f2bf(val);
}

// ---------------------------------------------------------------------------
// Stencil + transpose: grid'[b][y][x] = sum_s M9[s][y,x] * c[b][y+dy][x+dx],
// with cell (0,0) extracted to g00[b] (fp32, exact rank-1 path) and zeroed.
// Output layout B1t[(b*320+x)][y'] bf16 (k-contiguous for stage-1 B-frags).
// 32x32 tile per block, LDS transpose, 8B packed stores.
// ---------------------------------------------------------------------------
__global__ __launch_bounds__(256) void stencil_t(const float2* __restrict__ ksp,
                                                 const float* __restrict__ M9,
                                                 short* __restrict__ B1t,
                                                 float* __restrict__ g00) {
    __shared__ float2 Ls[32][33];
    int b = blockIdx.z;
    int tx0 = blockIdx.x * 32, ty0 = blockIdx.y * 32;
    int tid = threadIdx.x;
    int xl = tid & 31, yq = tid >> 5;
    const float2* kb = ksp + (size_t)b * CELLS;
#pragma unroll
    for (int rr = 0; rr < 4; rr++) {
        int yl = yq + 8 * rr;
        int y = ty0 + yl, x = tx0 + xl;
        int cell = y * RES + x;
        float re = 0.f, im = 0.f;
#pragma unroll
        for (int s = 0; s < 9; s++) {
            float w = M9[s * CELLS + cell];
            int dy = s / 3 - 1, dx = s % 3 - 1;
            int yn = min(max(y + dy, 0), RES - 1);
            int xn = min(max(x + dx, 0), RES - 1);
            float2 v = kb[yn * RES + xn];
            re = fmaf(w, v.x, re);
            im = fmaf(w, v.y, im);
        }
        if (cell == 0) {  // rank-1 extraction: exact fp32 path for the huge DC term
            g00[2 * b] = re;
            g00[2 * b + 1] = im;
            re = 0.f;
            im = 0.f;
        }
        Ls[yl][xl] = make_float2(re, im);
    }
    __syncthreads();
    int xc = tid >> 3, yg = tid & 7;
    float2 v0 = Ls[yg * 4 + 0][xc], v1 = Ls[yg * 4 + 1][xc];
    float2 v2 = Ls[yg * 4 + 2][xc], v3 = Ls[yg * 4 + 3][xc];
    uint2 pr, pi;
    pr.x = (unsigned short)f2bf(v0.x) | ((unsigned)(unsigned short)f2bf(v1.x) << 16);
    pr.y = (unsigned short)f2bf(v2.x) | ((unsigned)(unsigned short)f2bf(v3.x) << 16);
    pi.x = (unsigned short)f2bf(v0.y) | ((unsigned)(unsigned short)f2bf(v1.y) << 16);
    pi.y = (unsigned short)f2bf(v2.y) | ((unsigned)(unsigned short)f2bf(v3.y) << 16);
    size_t rowbase = ((size_t)b * RES + tx0 + xc) * MDIM;
    *(uint2*)(B1t + rowbase + ty0 + yg * 4) = pr;
    *(uint2*)(B1t + rowbase + RES + ty0 + yg * 4) = pi;
}

// ---------------------------------------------------------------------------
// Stage 1: C1[m'][(b,x)] = sum_y' F1[m'][y'] * B1t[(b,x)][y']
// M=640, N=10240, K=640. 128x128 tile, BK=32, 4 waves x 4x4 16x16x32 MFMA.
// ---------------------------------------------------------------------------
__global__ __launch_bounds__(256) void gemm1(const short* __restrict__ F1,
                                             const short* __restrict__ B1t,
                                             short* __restrict__ C1) {
    __shared__ short At[128 * 32];
    __shared__ short Bt[128 * 32];
    int tid = threadIdx.x;
    int lane = tid & 63, wave = tid >> 6;
    int wr = wave >> 1, wc = wave & 1;
    int m0 = blockIdx.y * 128, n0 = blockIdx.x * 128;
    int q = lane >> 4, tl = lane & 15;
    f32x4 acc[4][4];
#pragma unroll
    for (int i = 0; i < 4; i++)
#pragma unroll
        for (int j = 0; j < 4; j++) acc[i][j] = {0.f, 0.f, 0.f, 0.f};

    for (int kt = 0; kt < 20; kt++) {
        int k0 = kt * 32;
#pragma unroll
        for (int r = 0; r < 2; r++) {
            int c = r * 256 + tid;
            int row = c >> 2, koff = (c & 3) * 8;
            GLD16(F1 + (size_t)(m0 + row) * MDIM + k0 + koff,
                  At + (size_t)(r * 256 + wave * 64) * 8);
            GLD16(B1t + (size_t)(n0 + row) * MDIM + k0 + koff,
                  Bt + (size_t)(r * 256 + wave * 64) * 8);
        }
        __syncthreads();
        short8 a[4], bf[4];
#pragma unroll
        for (int i = 0; i < 4; i++)
            a[i] = *(const short8*)&At[(wr * 64 + i * 16 + tl) * 32 + q * 8];
#pragma unroll
        for (int j = 0; j < 4; j++)
            bf[j] = *(const short8*)&Bt[(wc * 64 + j * 16 + tl) * 32 + q * 8];
#pragma unroll
        for (int i = 0; i < 4; i++)
#pragma unroll
            for (int j = 0; j < 4; j++)
                acc[i][j] = __builtin_amdgcn_mfma_f32_16x16x32_bf16(a[i], bf[j], acc[i][j], 0, 0, 0);
        __syncthreads();
    }
#pragma unroll
    for (int i = 0; i < 4; i++)
#pragma unroll
        for (int j = 0; j < 4; j++)
#pragma unroll
            for (int t = 0; t < 4; t++) {
                int mrow = m0 + wr * 64 + i * 16 + q * 4 + t;
                int ncol = n0 + wc * 64 + j * 16 + tl;
                C1[(size_t)mrow * NCOLS + ncol] = f2bf(acc[i][j][t]);
            }
}

// ---------------------------------------------------------------------------
// Stage 2: out[(b,m)][n'] = sum_x' T2[(b,m)][x'] * F1[n'][x']  where
// T2[(b,m)][x+320*ct] = C1[m+320*ct][b*320+x]  (k-run exists contiguously in
// C1 -> per-lane addressed global_load_lds, no transpose kernel needed).
// Epilogue adds the rank-1 checkerboard g00[b]*(-1)^(m+n) and writes planar out.
// ---------------------------------------------------------------------------
__global__ __launch_bounds__(256) void gemm2(const short* __restrict__ C1,
                                             const short* __restrict__ F1,
                                             const float* __restrict__ g00,
                                             float* __restrict__ out) {
    __shared__ short At[128 * 32];
    __shared__ short Bt[128 * 32];
    int tid = threadIdx.x;
    int lane = tid & 63, wave = tid >> 6;
    int wr = wave >> 1, wc = wave & 1;
    int r0 = blockIdx.y * 128, n0 = blockIdx.x * 128;
    int q = lane >> 4, tl = lane & 15;
    f32x4 acc[4][4];
#pragma unroll
    for (int i = 0; i < 4; i++)
#pragma unroll
        for (int j = 0; j < 4; j++) acc[i][j] = {0.f, 0.f, 0.f, 0.f};

    for (int kt = 0; kt < 20; kt++) {
        int k0 = kt * 32;
        int ct = (k0 >= RES) ? 1 : 0;
        int kk = k0 - RES * ct;
#pragma unroll
        for (int r = 0; r < 2; r++) {
            int c = r * 256 + tid;
            int row = c >> 2, koff = (c & 3) * 8;
            int gr = r0 + row;
            unsigned bb = (unsigned)gr / 320u;
            int m = gr - (int)bb * 320;
            GLD16(C1 + (size_t)(m + RES * ct) * NCOLS + bb * RES + kk + koff,
                  At + (size_t)(r * 256 + wave * 64) * 8);
            GLD16(F1 + (size_t)(n0 + row) * MDIM + k0 + koff,
                  Bt + (size_t)(r * 256 + wave * 64) * 8);
        }
        __syncthreads();
        short8 a[4], bf[4];
#pragma unroll
        for (int i = 0; i < 4; i++)
            a[i] = *(const short8*)&At[(wr * 64 + i * 16 + tl) * 32 + q * 8];
#pragma unroll
        for (int j = 0; j < 4; j++)
            bf[j] = *(const short8*)&Bt[(wc * 64 + j * 16 + tl) * 32 + q * 8];
#pragma unroll
        for (int i = 0; i < 4; i++)
#pragma unroll
            for (int j = 0; j < 4; j++)
                acc[i][j] = __builtin_amdgcn_mfma_f32_16x16x32_bf16(a[i], bf[j], acc[i][j], 0, 0, 0);
        __syncthreads();
    }
#pragma unroll
    for (int i = 0; i < 4; i++)
#pragma unroll
        for (int j = 0; j < 4; j++) {
            int npcol = n0 + wc * 64 + j * 16 + tl;
            int comp = npcol >= RES;
            int n = npcol - RES * comp;
#pragma unroll
            for (int t = 0; t < 4; t++) {
                int gr = r0 + wr * 64 + i * 16 + q * 4 + t;
                unsigned bb = (unsigned)gr / 320u;
                int m = gr - (int)bb * 320;
                float g = g00[2 * bb + comp];
                float sgn = ((m + n) & 1) ? -1.0f : 1.0f;
                out[(((size_t)bb * 2 + comp) * RES + m) * RES + n] = acc[i][j][t] + sgn * g;
            }
        }
}

extern "C" void kernel_launch(void* const* d_in, const int* in_sizes, int n_in,
                              void* d_out, int out_size, void* d_ws, size_t ws_size,
                              hipStream_t stream) {
    const float* ksp = (const float*)d_in[0];
    const float* traj = (const float*)d_in[1];
    int P = in_sizes[1] / 2;  // 102400

    // Workspace: M9 (9*CELLS f32) | F1 (640*640 bf16) | B1t (10240*640 bf16)
    //            | C1 (10240*640 bf16) | g00 (32 float2)
    float* ws = (float*)d_ws;
    float* M9 = ws;
    short* F1 = (short*)(M9 + (size_t)9 * CELLS);
    short* B1t = F1 + (size_t)MDIM * MDIM;
    short* C1 = B1t + (size_t)NCOLS * MDIM;
    float* g00 = (float*)(C1 + (size_t)NCOLS * MDIM);

    hipMemsetAsync(M9, 0, (size_t)9 * CELLS * sizeof(float), stream);
    build_m9<<<(P + 255) / 256, 256, 0, stream>>>(traj, P, M9);
    make_F1<<<(MDIM * MDIM + 255) / 256, 256, 0, stream>>>(F1);
    stencil_t<<<dim3(10, 10, 32), 256, 0, stream>>>((const float2*)ksp, M9, B1t, g00);
    gemm1<<<dim3(80, 5), 256, 0, stream>>>(F1, B1t, C1);
    gemm2<<<dim3(5, 80), 256, 0, stream>>>(C1, F1, g00, (float*)d_out);
}

// Round 3
// 191.403 us; speedup vs baseline: 2.1872x; 1.0598x over previous
//
#include <hip/hip_runtime.h>

#define RES 320
#define CELLS (RES * RES)
#define MDIM 640      // 2*RES (Re/Im stacked)
#define NCOLS 10240   // 32 batches * RES

typedef __attribute__((ext_vector_type(8))) short short8;
typedef __attribute__((ext_vector_type(4))) float f32x4;

// round-to-nearest-even f32 -> bf16 bits (all values finite here)
static __device__ __forceinline__ short f2bf(float f) {
    unsigned u = __builtin_bit_cast(unsigned, f);
    unsigned r = (u + 0x7fffu + ((u >> 16) & 1u)) >> 16;
    return (short)r;
}

#define GLD16(g, l) __builtin_amdgcn_global_load_lds(                        \
    (const __attribute__((address_space(1))) void*)(g),                      \
    (__attribute__((address_space(3))) void*)(l), 16, 0, 0)

// ---------------------------------------------------------------------------
// Wave-level run-segmented atomic add: combines contiguous equal-key runs,
// one atomic per run (key < 0 => no atomic). Used only for the rare spill
// path (contributions outside a block's LDS window, e.g. degenerate points).
// ---------------------------------------------------------------------------
__device__ __forceinline__ void seg_atomic_add(float* base, int key, float val, int lane) {
    int prev = __shfl_up(key, 1);
    bool head = (lane == 0) || (prev != key);
    unsigned long long hb = __ballot(head);
    unsigned long long below = (lane == 63) ? hb : (hb & ((1ULL << (lane + 1)) - 1ULL));
    int run_start = 63 - __clzll(below);
#pragma unroll
    for (int d = 1; d < 64; d <<= 1) {
        float o = __shfl_up(val, d);
        if (lane - d >= run_start) val += o;
    }
    bool tail = (lane == 63) || ((hb >> (lane + 1)) & 1ULL);
    if (tail && key >= 0) atomicAdd(base + key, val);
}

// ---------------------------------------------------------------------------
// Build 9-point stencil weights M9 via banded LDS privatization.
// Block b handles the 2560 points with J in [8b, 8b+8); their in-bounds
// scatter targets have cy in [8b-1, 8b+7] -> LDS window acc[9][9][320].
// thread = I coordinate => LDS atomics hit consecutive banks (conflict-free).
// Flush: interior rows (w=1..7) owned exclusively -> plain float4 stores;
// boundary rows (w=0,8) shared with one neighbor band -> global atomics.
// Out-of-window targets (degenerate trajectory points) -> seg-atomic into
// the spill plane M9s, merged later. Global fp-atomic count drops ~10x.
// ---------------------------------------------------------------------------
__global__ __launch_bounds__(320) void build_m9(const float* __restrict__ traj,
                                                float* __restrict__ M9,
                                                float* __restrict__ M9s) {
    __shared__ float acc[9 * 9 * RES];
    int blk = blockIdx.x;   // 0..39
    int J0 = blk * 8;
    int cyBase = J0 - 1;
    int tid = threadIdx.x;  // 0..319 == I
    int lane = tid & 63;
    for (int i = tid; i < 9 * 9 * RES; i += 320) acc[i] = 0.f;
    __syncthreads();

    const float4* tp = (const float4*)(traj + ((size_t)tid * RES + J0) * 2);
    float4 pv0 = tp[0], pv1 = tp[1], pv2 = tp[2], pv3 = tp[3];
    float t0v[8] = {pv0.x, pv0.z, pv1.x, pv1.z, pv2.x, pv2.z, pv3.x, pv3.z};
    float t1v[8] = {pv0.y, pv0.w, pv1.y, pv1.w, pv2.y, pv2.w, pv3.y, pv3.w};

    const int ox[4] = {0, 1, 0, 1};
    const int oy[4] = {0, 0, 1, 1};
#pragma unroll
    for (int jj = 0; jj < 8; jj++) {
        float x = ((t0v[jj] * (2.0f / RES) + 1.0f) * RES - 1.0f) * 0.5f;
        float y = ((t1v[jj] * (2.0f / RES) + 1.0f) * RES - 1.0f) * 0.5f;
        float x0f = floorf(x), y0f = floorf(y);
        float fx = x - x0f, fy = y - y0f;
        int x0 = (int)x0f, y0 = (int)y0f;
        float w[4] = {(1.f - fx) * (1.f - fy), fx * (1.f - fy), (1.f - fx) * fy, fx * fy};
        int cxv[4], cyv[4];
        bool v[4];
#pragma unroll
        for (int k = 0; k < 4; k++) {
            int cx = x0 + ox[k], cy = y0 + oy[k];
            v[k] = (cx >= 0) && (cx < RES) && (cy >= 0) && (cy < RES);
            cxv[k] = cx;
            cyv[k] = cy;
        }
#pragma unroll
        for (int j = 0; j < 4; j++) {
#pragma unroll
            for (int i = 0; i < 4; i++) {
                int slot = (oy[i] - oy[j] + 1) * 3 + (ox[i] - ox[j] + 1);
                bool valid = v[i] && v[j];
                int wr = cyv[j] - cyBase;
                bool inwin = valid && ((unsigned)wr < 9u);
                if (inwin)
                    atomicAdd(&acc[(slot * 9 + wr) * RES + cxv[j]], w[j] * w[i]);
                bool sp = valid && !inwin;
                if (__ballot(sp))
                    seg_atomic_add(M9s + (size_t)slot * CELLS,
                                   sp ? cyv[j] * RES + cxv[j] : -1, w[j] * w[i], lane);
            }
        }
    }
    __syncthreads();
    for (int i = tid; i < 9 * 9 * (RES / 4); i += 320) {
        int q = i % (RES / 4);
        int sr = i / (RES / 4);
        int w = sr % 9;
        int slot = sr / 9;
        int cy = cyBase + w;
        if (cy < 0 || cy >= RES) continue;
        float4 v4 = *(const float4*)&acc[sr * RES + q * 4];
        float* dst = M9 + (size_t)slot * CELLS + (size_t)cy * RES + q * 4;
        if (w == 0 || w == 8) {  // shared with neighbor band
            if (v4.x != 0.f) atomicAdd(dst + 0, v4.x);
            if (v4.y != 0.f) atomicAdd(dst + 1, v4.y);
            if (v4.z != 0.f) atomicAdd(dst + 2, v4.z);
            if (v4.w != 0.f) atomicAdd(dst + 3, v4.w);
        } else {                 // exclusively owned row
            *(float4*)dst = v4;
        }
    }
}

// Fold the (sparse) spill plane into M9.
__global__ __launch_bounds__(256) void merge_m9(float* __restrict__ M9,
                                                const float* __restrict__ M9s) {
    int i = blockIdx.x * 256 + threadIdx.x;
    if (i >= 9 * CELLS) return;
    float s = M9s[i];
    if (s != 0.f) M9[i] += s;
}

// ---------------------------------------------------------------------------
// F1[m'][y'] bf16, 640x640: block matrix [[Fr,-Fi],[Fi,Fr]] of
// F[u,y] = (-1)^(u+y) exp(+2*pi*i*u*y/RES). Serves as stage-1 A and stage-2 B.
// ---------------------------------------------------------------------------
__global__ __launch_bounds__(256) void make_F1(short* __restrict__ F1) {
    int idx = blockIdx.x * 256 + threadIdx.x;
    if (idx >= MDIM * MDIM) return;
    int mp = idx / MDIM, yp = idx % MDIM;
    int cm = mp >= RES, cy = yp >= RES;
    int m = mp - RES * cm, y = yp - RES * cy;
    int r = (m * y) % RES;
    float s, c;
    sincospif((float)r * (2.0f / RES), &s, &c);
    float sign = ((m + y) & 1) ? -1.0f : 1.0f;
    float fr = sign * c, fi = sign * s;
    float val = (cm == 0) ? (cy == 0 ? fr : -fi) : (cy == 0 ? fi : fr);
    F1[idx] = f2bf(val);
}

// ---------------------------------------------------------------------------
// Stencil + transpose: grid'[b][y][x] = sum_s M9[s][y,x] * c[b][y+dy][x+dx],
// cell (0,0) extracted to g00[b] (exact fp32 rank-1 path) and zeroed.
// Output B1t[(b*320+x)][y'] bf16 (k-contiguous for stage-1 B-frags).
// ---------------------------------------------------------------------------
__global__ __launch_bounds__(256) void stencil_t(const float2* __restrict__ ksp,
                                                 const float* __restrict__ M9,
                                                 short* __restrict__ B1t,
                                                 float* __restrict__ g00) {
    __shared__ float2 Ls[32][33];
    int b = blockIdx.z;
    int tx0 = blockIdx.x * 32, ty0 = blockIdx.y * 32;
    int tid = threadIdx.x;
    int xl = tid & 31, yq = tid >> 5;
    const float2* kb = ksp + (size_t)b * CELLS;
#pragma unroll
    for (int rr = 0; rr < 4; rr++) {
        int yl = yq + 8 * rr;
        int y = ty0 + yl, x = tx0 + xl;
        int cell = y * RES + x;
        float re = 0.f, im = 0.f;
#pragma unroll
        for (int s = 0; s < 9; s++) {
            float w = M9[s * CELLS + cell];
            int dy = s / 3 - 1, dx = s % 3 - 1;
            int yn = min(max(y + dy, 0), RES - 1);
            int xn = min(max(x + dx, 0), RES - 1);
            float2 v = kb[yn * RES + xn];
            re = fmaf(w, v.x, re);
            im = fmaf(w, v.y, im);
        }
        if (cell == 0) {
            g00[2 * b] = re;
            g00[2 * b + 1] = im;
            re = 0.f;
            im = 0.f;
        }
        Ls[yl][xl] = make_float2(re, im);
    }
    __syncthreads();
    int xc = tid >> 3, yg = tid & 7;
    float2 v0 = Ls[yg * 4 + 0][xc], v1 = Ls[yg * 4 + 1][xc];
    float2 v2 = Ls[yg * 4 + 2][xc], v3 = Ls[yg * 4 + 3][xc];
    uint2 pr, pi;
    pr.x = (unsigned short)f2bf(v0.x) | ((unsigned)(unsigned short)f2bf(v1.x) << 16);
    pr.y = (unsigned short)f2bf(v2.x) | ((unsigned)(unsigned short)f2bf(v3.x) << 16);
    pi.x = (unsigned short)f2bf(v0.y) | ((unsigned)(unsigned short)f2bf(v1.y) << 16);
    pi.y = (unsigned short)f2bf(v2.y) | ((unsigned)(unsigned short)f2bf(v3.y) << 16);
    size_t rowbase = ((size_t)b * RES + tx0 + xc) * MDIM;
    *(uint2*)(B1t + rowbase + ty0 + yg * 4) = pr;
    *(uint2*)(B1t + rowbase + RES + ty0 + yg * 4) = pi;
}

// ---------------------------------------------------------------------------
// Stage 1: C1[m'][(b,x)] = sum_y' F1[m'][y'] * B1t[(b,x)][y']
// M=640, N=10240, K=640. 128x128 tile, BK=32, 4 waves x 4x4 16x16x32 MFMA.
// ---------------------------------------------------------------------------
__global__ __launch_bounds__(256) void gemm1(const short* __restrict__ F1,
                                             const short* __restrict__ B1t,
                                             short* __restrict__ C1) {
    __shared__ short At[128 * 32];
    __shared__ short Bt[128 * 32];
    int tid = threadIdx.x;
    int lane = tid & 63, wave = tid >> 6;
    int wr = wave >> 1, wc = wave & 1;
    int m0 = blockIdx.y * 128, n0 = blockIdx.x * 128;
    int q = lane >> 4, tl = lane & 15;
    f32x4 acc[4][4];
#pragma unroll
    for (int i = 0; i < 4; i++)
#pragma unroll
        for (int j = 0; j < 4; j++) acc[i][j] = {0.f, 0.f, 0.f, 0.f};

    for (int kt = 0; kt < 20; kt++) {
        int k0 = kt * 32;
#pragma unroll
        for (int r = 0; r < 2; r++) {
            int c = r * 256 + tid;
            int row = c >> 2, koff = (c & 3) * 8;
            GLD16(F1 + (size_t)(m0 + row) * MDIM + k0 + koff,
                  At + (size_t)(r * 256 + wave * 64) * 8);
            GLD16(B1t + (size_t)(n0 + row) * MDIM + k0 + koff,
                  Bt + (size_t)(r * 256 + wave * 64) * 8);
        }
        __syncthreads();
        short8 a[4], bf[4];
#pragma unroll
        for (int i = 0; i < 4; i++)
            a[i] = *(const short8*)&At[(wr * 64 + i * 16 + tl) * 32 + q * 8];
#pragma unroll
        for (int j = 0; j < 4; j++)
            bf[j] = *(const short8*)&Bt[(wc * 64 + j * 16 + tl) * 32 + q * 8];
#pragma unroll
        for (int i = 0; i < 4; i++)
#pragma unroll
            for (int j = 0; j < 4; j++)
                acc[i][j] = __builtin_amdgcn_mfma_f32_16x16x32_bf16(a[i], bf[j], acc[i][j], 0, 0, 0);
        __syncthreads();
    }
#pragma unroll
    for (int i = 0; i < 4; i++)
#pragma unroll
        for (int j = 0; j < 4; j++)
#pragma unroll
            for (int t = 0; t < 4; t++) {
                int mrow = m0 + wr * 64 + i * 16 + q * 4 + t;
                int ncol = n0 + wc * 64 + j * 16 + tl;
                C1[(size_t)mrow * NCOLS + ncol] = f2bf(acc[i][j][t]);
            }
}

// ---------------------------------------------------------------------------
// Stage 2: out[(b,m)][n'] = sum_x' T2[(b,m)][x'] * F1[n'][x'], with
// T2[(b,m)][x+320*ct] = C1[m+320*ct][b*320+x]. Epilogue adds the rank-1
// checkerboard g00[b]*(-1)^(m+n) and writes planar out (b,1,2,H,W).
// ---------------------------------------------------------------------------
__global__ __launch_bounds__(256) void gemm2(const short* __restrict__ C1,
                                             const short* __restrict__ F1,
                                             const float* __restrict__ g00,
                                             float* __restrict__ out) {
    __shared__ short At[128 * 32];
    __shared__ short Bt[128 * 32];
    int tid = threadIdx.x;
    int lane = tid & 63, wave = tid >> 6;
    int wr = wave >> 1, wc = wave & 1;
    int r0 = blockIdx.y * 128, n0 = blockIdx.x * 128;
    int q = lane >> 4, tl = lane & 15;
    f32x4 acc[4][4];
#pragma unroll
    for (int i = 0; i < 4; i++)
#pragma unroll
        for (int j = 0; j < 4; j++) acc[i][j] = {0.f, 0.f, 0.f, 0.f};

    for (int kt = 0; kt < 20; kt++) {
        int k0 = kt * 32;
        int ct = (k0 >= RES) ? 1 : 0;
        int kk = k0 - RES * ct;
#pragma unroll
        for (int r = 0; r < 2; r++) {
            int c = r * 256 + tid;
            int row = c >> 2, koff = (c & 3) * 8;
            int gr = r0 + row;
            unsigned bb = (unsigned)gr / 320u;
            int m = gr - (int)bb * 320;
            GLD16(C1 + (size_t)(m + RES * ct) * NCOLS + bb * RES + kk + koff,
                  At + (size_t)(r * 256 + wave * 64) * 8);
            GLD16(F1 + (size_t)(n0 + row) * MDIM + k0 + koff,
                  Bt + (size_t)(r * 256 + wave * 64) * 8);
        }
        __syncthreads();
        short8 a[4], bf[4];
#pragma unroll
        for (int i = 0; i < 4; i++)
            a[i] = *(const short8*)&At[(wr * 64 + i * 16 + tl) * 32 + q * 8];
#pragma unroll
        for (int j = 0; j < 4; j++)
            bf[j] = *(const short8*)&Bt[(wc * 64 + j * 16 + tl) * 32 + q * 8];
#pragma unroll
        for (int i = 0; i < 4; i++)
#pragma unroll
            for (int j = 0; j < 4; j++)
                acc[i][j] = __builtin_amdgcn_mfma_f32_16x16x32_bf16(a[i], bf[j], acc[i][j], 0, 0, 0);
        __syncthreads();
    }
#pragma unroll
    for (int i = 0; i < 4; i++)
#pragma unroll
        for (int j = 0; j < 4; j++) {
            int npcol = n0 + wc * 64 + j * 16 + tl;
            int comp = npcol >= RES;
            int n = npcol - RES * comp;
#pragma unroll
            for (int t = 0; t < 4; t++) {
                int gr = r0 + wr * 64 + i * 16 + q * 4 + t;
                unsigned bb = (unsigned)gr / 320u;
                int m = gr - (int)bb * 320;
                float g = g00[2 * bb + comp];
                float sgn = ((m + n) & 1) ? -1.0f : 1.0f;
                out[(((size_t)bb * 2 + comp) * RES + m) * RES + n] = acc[i][j][t] + sgn * g;
            }
        }
}

extern "C" void kernel_launch(void* const* d_in, const int* in_sizes, int n_in,
                              void* d_out, int out_size, void* d_ws, size_t ws_size,
                              hipStream_t stream) {
    const float* ksp = (const float*)d_in[0];
    const float* traj = (const float*)d_in[1];

    // Workspace: M9 (9*CELLS f32) | M9s (9*CELLS f32) | F1 (640*640 bf16)
    //            | B1t (10240*640 bf16) | C1 (10240*640 bf16) | g00 (32 float2)
    float* ws = (float*)d_ws;
    float* M9 = ws;
    float* M9s = ws + (size_t)9 * CELLS;
    short* F1 = (short*)(ws + (size_t)18 * CELLS);
    short* B1t = F1 + (size_t)MDIM * MDIM;
    short* C1 = B1t + (size_t)NCOLS * MDIM;
    float* g00 = (float*)(C1 + (size_t)NCOLS * MDIM);

    hipMemsetAsync(M9, 0, (size_t)18 * CELLS * sizeof(float), stream);
    build_m9<<<40, 320, 0, stream>>>(traj, M9, M9s);
    make_F1<<<(MDIM * MDIM + 255) / 256, 256, 0, stream>>>(F1);
    merge_m9<<<(9 * CELLS + 255) / 256, 256, 0, stream>>>(M9, M9s);
    stencil_t<<<dim3(10, 10, 32), 256, 0, stream>>>((const float2*)ksp, M9, B1t, g00);
    gemm1<<<dim3(80, 5), 256, 0, stream>>>(F1, B1t, C1);
    gemm2<<<dim3(5, 80), 256, 0, stream>>>(C1, F1, g00, (float*)d_out);
}

// Round 4
// 170.882 us; speedup vs baseline: 2.4498x; 1.1201x over previous
//
#include <hip/hip_runtime.h>

#define RES 320
#define CELLS (RES * RES)
#define MDIM 640      // 2*RES (Re/Im stacked)
#define NCOLS 10240   // 32 batches * RES
#define NJ 4          // J rows per build_m9 band
#define WROWS (NJ + 1)

typedef __attribute__((ext_vector_type(8))) short short8;
typedef __attribute__((ext_vector_type(4))) float f32x4;

// round-to-nearest-even f32 -> bf16 bits (all values finite here)
static __device__ __forceinline__ short f2bf(float f) {
    unsigned u = __builtin_bit_cast(unsigned, f);
    unsigned r = (u + 0x7fffu + ((u >> 16) & 1u)) >> 16;
    return (short)r;
}

#define GLD16(g, l) __builtin_amdgcn_global_load_lds(                        \
    (const __attribute__((address_space(1))) void*)(g),                      \
    (__attribute__((address_space(3))) void*)(l), 16, 0, 0)

// ---------------------------------------------------------------------------
// Wave-level run-segmented atomic add: combines contiguous equal-key runs,
// one atomic per run (key < 0 => no atomic). Only called at final flush
// (16 calls/thread total), where degenerate lanes hold identical keys.
// ---------------------------------------------------------------------------
__device__ __forceinline__ void seg_atomic_add(float* base, int key, float val, int lane) {
    int prev = __shfl_up(key, 1);
    bool head = (lane == 0) || (prev != key);
    unsigned long long hb = __ballot(head);
    unsigned long long below = (lane == 63) ? hb : (hb & ((1ULL << (lane + 1)) - 1ULL));
    int run_start = 63 - __clzll(below);
#pragma unroll
    for (int d = 1; d < 64; d <<= 1) {
        float o = __shfl_up(val, d);
        if (lane - d >= run_start) val += o;
    }
    bool tail = (lane == 63) || ((hb >> (lane + 1)) & 1ULL);
    if (tail && key >= 0) atomicAdd(base + key, val);
}

// ---------------------------------------------------------------------------
// Build M9 via banded LDS privatization + per-pair register accumulation.
// Block b: points with J in [NJ*b, NJ*b+NJ); in-bounds targets have
// cy in [J0-1, J0+NJ-1] -> LDS window acc[9][WROWS][320].
// Each of the 16 (scatter j, gather i) pairs keeps a lazy {key,val} register
// pair for LDS and for global spill; atomics fire only on key change or at
// the end. Normal points: key changes every jj -> plain conflict-free ds_add
// (lanes = consecutive I = consecutive banks). Degenerate (skipped) points:
// key is constant -> one combined emit, spills folded by seg_atomic_add.
// ---------------------------------------------------------------------------
__global__ __launch_bounds__(320) void build_m9(const float* __restrict__ traj,
                                                float* __restrict__ M9,
                                                float* __restrict__ M9s) {
    __shared__ float acc[9 * WROWS * RES];
    int blk = blockIdx.x;   // 0..(320/NJ-1)
    int J0 = blk * NJ;
    int cyBase = J0 - 1;
    int tid = threadIdx.x;  // 0..319 == I
    int lane = tid & 63;
    for (int i = tid; i < 9 * WROWS * RES; i += 320) acc[i] = 0.f;
    __syncthreads();

    const float4* tp = (const float4*)(traj + ((size_t)tid * RES + J0) * 2);
    float t0v[NJ], t1v[NJ];
#pragma unroll
    for (int h = 0; h < NJ / 2; h++) {
        float4 pv = tp[h];
        t0v[2 * h] = pv.x; t1v[2 * h] = pv.y;
        t0v[2 * h + 1] = pv.z; t1v[2 * h + 1] = pv.w;
    }

    const int ox[4] = {0, 1, 0, 1};
    const int oy[4] = {0, 0, 1, 1};
    int lkey[16], gkey[16];
    float lval[16], gval[16];
#pragma unroll
    for (int p = 0; p < 16; p++) { lkey[p] = -1; gkey[p] = -1; lval[p] = 0.f; gval[p] = 0.f; }

#pragma unroll
    for (int jj = 0; jj < NJ; jj++) {
        float x = ((t0v[jj] * (2.0f / RES) + 1.0f) * RES - 1.0f) * 0.5f;
        float y = ((t1v[jj] * (2.0f / RES) + 1.0f) * RES - 1.0f) * 0.5f;
        float x0f = floorf(x), y0f = floorf(y);
        float fx = x - x0f, fy = y - y0f;
        int x0 = (int)x0f, y0 = (int)y0f;
        float w[4] = {(1.f - fx) * (1.f - fy), fx * (1.f - fy), (1.f - fx) * fy, fx * fy};
        int cxv[4], cyv[4];
        bool v[4];
#pragma unroll
        for (int k = 0; k < 4; k++) {
            int cx = x0 + ox[k], cy = y0 + oy[k];
            v[k] = (cx >= 0) && (cx < RES) && (cy >= 0) && (cy < RES);
            cxv[k] = cx;
            cyv[k] = cy;
        }
#pragma unroll
        for (int j = 0; j < 4; j++) {
#pragma unroll
            for (int i = 0; i < 4; i++) {
                int p = j * 4 + i;
                int slot = (oy[i] - oy[j] + 1) * 3 + (ox[i] - ox[j] + 1);
                bool valid = v[i] && v[j];
                float wv = w[j] * w[i];
                int wr = cyv[j] - cyBase;
                bool inwin = valid && ((unsigned)wr < (unsigned)WROWS);
                if (inwin) {
                    int k = (slot * WROWS + wr) * RES + cxv[j];
                    if (k == lkey[p]) {
                        lval[p] += wv;
                    } else {
                        if (lkey[p] >= 0) atomicAdd(&acc[lkey[p]], lval[p]);
                        lkey[p] = k;
                        lval[p] = wv;
                    }
                } else if (valid) {
                    int g = slot * CELLS + cyv[j] * RES + cxv[j];
                    if (g == gkey[p]) {
                        gval[p] += wv;
                    } else {
                        if (gkey[p] >= 0) atomicAdd(M9s + gkey[p], gval[p]);
                        gkey[p] = g;
                        gval[p] = wv;
                    }
                }
            }
        }
    }
    // Final flush: LDS per-lane; global via wave-segmented combine (degenerate
    // lanes are contiguous in I and share identical keys).
#pragma unroll
    for (int p = 0; p < 16; p++) {
        if (lkey[p] >= 0) atomicAdd(&acc[lkey[p]], lval[p]);
        seg_atomic_add(M9s, gkey[p], gval[p], lane);
    }
    __syncthreads();
    for (int i = tid; i < 9 * WROWS * (RES / 4); i += 320) {
        int q = i % (RES / 4);
        int sr = i / (RES / 4);
        int w = sr % WROWS;
        int slot = sr / WROWS;
        int cy = cyBase + w;
        if (cy < 0 || cy >= RES) continue;
        float4 v4 = *(const float4*)&acc[sr * RES + q * 4];
        float* dst = M9 + (size_t)slot * CELLS + (size_t)cy * RES + q * 4;
        if (w == 0 || w == WROWS - 1) {  // shared with neighbor band
            if (v4.x != 0.f) atomicAdd(dst + 0, v4.x);
            if (v4.y != 0.f) atomicAdd(dst + 1, v4.y);
            if (v4.z != 0.f) atomicAdd(dst + 2, v4.z);
            if (v4.w != 0.f) atomicAdd(dst + 3, v4.w);
        } else {                         // exclusively owned row
            *(float4*)dst = v4;
        }
    }
}

// Fold the (sparse) spill plane into M9.
__global__ __launch_bounds__(256) void merge_m9(float* __restrict__ M9,
                                                const float* __restrict__ M9s) {
    int i = blockIdx.x * 256 + threadIdx.x;
    if (i >= 9 * CELLS) return;
    float s = M9s[i];
    if (s != 0.f) M9[i] += s;
}

// ---------------------------------------------------------------------------
// F1[m'][y'] bf16, 640x640: block matrix [[Fr,-Fi],[Fi,Fr]] of
// F[u,y] = (-1)^(u+y) exp(+2*pi*i*u*y/RES). Serves as stage-1 A and stage-2 B.
// ---------------------------------------------------------------------------
__global__ __launch_bounds__(256) void make_F1(short* __restrict__ F1) {
    int idx = blockIdx.x * 256 + threadIdx.x;
    if (idx >= MDIM * MDIM) return;
    int mp = idx / MDIM, yp = idx % MDIM;
    int cm = mp >= RES, cy = yp >= RES;
    int m = mp - RES * cm, y = yp - RES * cy;
    int r = (m * y) % RES;
    float s, c;
    sincospif((float)r * (2.0f / RES), &s, &c);
    float sign = ((m + y) & 1) ? -1.0f : 1.0f;
    float fr = sign * c, fi = sign * s;
    float val = (cm == 0) ? (cy == 0 ? fr : -fi) : (cy == 0 ? fi : fr);
    F1[idx] = f2bf(val);
}

// ---------------------------------------------------------------------------
// Stencil + transpose: grid'[b][y][x] = sum_s M9[s][y,x] * c[b][y+dy][x+dx],
// cell (0,0) extracted to g00[b] (exact fp32 rank-1 path) and zeroed.
// Output B1t[(b*320+x)][y'] bf16 (k-contiguous for stage-1 B-frags).
// ---------------------------------------------------------------------------
__global__ __launch_bounds__(256) void stencil_t(const float2* __restrict__ ksp,
                                                 const float* __restrict__ M9,
                                                 short* __restrict__ B1t,
                                                 float* __restrict__ g00) {
    __shared__ float2 Ls[32][33];
    int b = blockIdx.z;
    int tx0 = blockIdx.x * 32, ty0 = blockIdx.y * 32;
    int tid = threadIdx.x;
    int xl = tid & 31, yq = tid >> 5;
    const float2* kb = ksp + (size_t)b * CELLS;
#pragma unroll
    for (int rr = 0; rr < 4; rr++) {
        int yl = yq + 8 * rr;
        int y = ty0 + yl, x = tx0 + xl;
        int cell = y * RES + x;
        float re = 0.f, im = 0.f;
#pragma unroll
        for (int s = 0; s < 9; s++) {
            float w = M9[s * CELLS + cell];
            int dy = s / 3 - 1, dx = s % 3 - 1;
            int yn = min(max(y + dy, 0), RES - 1);
            int xn = min(max(x + dx, 0), RES - 1);
            float2 v = kb[yn * RES + xn];
            re = fmaf(w, v.x, re);
            im = fmaf(w, v.y, im);
        }
        if (cell == 0) {
            g00[2 * b] = re;
            g00[2 * b + 1] = im;
            re = 0.f;
            im = 0.f;
        }
        Ls[yl][xl] = make_float2(re, im);
    }
    __syncthreads();
    int xc = tid >> 3, yg = tid & 7;
    float2 v0 = Ls[yg * 4 + 0][xc], v1 = Ls[yg * 4 + 1][xc];
    float2 v2 = Ls[yg * 4 + 2][xc], v3 = Ls[yg * 4 + 3][xc];
    uint2 pr, pi;
    pr.x = (unsigned short)f2bf(v0.x) | ((unsigned)(unsigned short)f2bf(v1.x) << 16);
    pr.y = (unsigned short)f2bf(v2.x) | ((unsigned)(unsigned short)f2bf(v3.x) << 16);
    pi.x = (unsigned short)f2bf(v0.y) | ((unsigned)(unsigned short)f2bf(v1.y) << 16);
    pi.y = (unsigned short)f2bf(v2.y) | ((unsigned)(unsigned short)f2bf(v3.y) << 16);
    size_t rowbase = ((size_t)b * RES + tx0 + xc) * MDIM;
    *(uint2*)(B1t + rowbase + ty0 + yg * 4) = pr;
    *(uint2*)(B1t + rowbase + RES + ty0 + yg * 4) = pi;
}

// ---------------------------------------------------------------------------
// Stage 1: C1[m'][(b,x)] = sum_y' F1[m'][y'] * B1t[(b,x)][y']
// M=640, N=10240, K=640. 128x128 tile, BK=32, 4 waves x 4x4 16x16x32 MFMA.
// ---------------------------------------------------------------------------
__global__ __launch_bounds__(256) void gemm1(const short* __restrict__ F1,
                                             const short* __restrict__ B1t,
                                             short* __restrict__ C1) {
    __shared__ short At[128 * 32];
    __shared__ short Bt[128 * 32];
    int tid = threadIdx.x;
    int lane = tid & 63, wave = tid >> 6;
    int wr = wave >> 1, wc = wave & 1;
    int m0 = blockIdx.y * 128, n0 = blockIdx.x * 128;
    int q = lane >> 4, tl = lane & 15;
    f32x4 acc[4][4];
#pragma unroll
    for (int i = 0; i < 4; i++)
#pragma unroll
        for (int j = 0; j < 4; j++) acc[i][j] = {0.f, 0.f, 0.f, 0.f};

    for (int kt = 0; kt < 20; kt++) {
        int k0 = kt * 32;
#pragma unroll
        for (int r = 0; r < 2; r++) {
            int c = r * 256 + tid;
            int row = c >> 2, koff = (c & 3) * 8;
            GLD16(F1 + (size_t)(m0 + row) * MDIM + k0 + koff,
                  At + (size_t)(r * 256 + wave * 64) * 8);
            GLD16(B1t + (size_t)(n0 + row) * MDIM + k0 + koff,
                  Bt + (size_t)(r * 256 + wave * 64) * 8);
        }
        __syncthreads();
        short8 a[4], bf[4];
#pragma unroll
        for (int i = 0; i < 4; i++)
            a[i] = *(const short8*)&At[(wr * 64 + i * 16 + tl) * 32 + q * 8];
#pragma unroll
        for (int j = 0; j < 4; j++)
            bf[j] = *(const short8*)&Bt[(wc * 64 + j * 16 + tl) * 32 + q * 8];
#pragma unroll
        for (int i = 0; i < 4; i++)
#pragma unroll
            for (int j = 0; j < 4; j++)
                acc[i][j] = __builtin_amdgcn_mfma_f32_16x16x32_bf16(a[i], bf[j], acc[i][j], 0, 0, 0);
        __syncthreads();
    }
#pragma unroll
    for (int i = 0; i < 4; i++)
#pragma unroll
        for (int j = 0; j < 4; j++)
#pragma unroll
            for (int t = 0; t < 4; t++) {
                int mrow = m0 + wr * 64 + i * 16 + q * 4 + t;
                int ncol = n0 + wc * 64 + j * 16 + tl;
                C1[(size_t)mrow * NCOLS + ncol] = f2bf(acc[i][j][t]);
            }
}

// ---------------------------------------------------------------------------
// Stage 2: out[(b,m)][n'] = sum_x' T2[(b,m)][x'] * F1[n'][x'], with
// T2[(b,m)][x+320*ct] = C1[m+320*ct][b*320+x]. Epilogue adds the rank-1
// checkerboard g00[b]*(-1)^(m+n) and writes planar out (b,1,2,H,W).
// ---------------------------------------------------------------------------
__global__ __launch_bounds__(256) void gemm2(const short* __restrict__ C1,
                                             const short* __restrict__ F1,
                                             const float* __restrict__ g00,
                                             float* __restrict__ out) {
    __shared__ short At[128 * 32];
    __shared__ short Bt[128 * 32];
    int tid = threadIdx.x;
    int lane = tid & 63, wave = tid >> 6;
    int wr = wave >> 1, wc = wave & 1;
    int r0 = blockIdx.y * 128, n0 = blockIdx.x * 128;
    int q = lane >> 4, tl = lane & 15;
    f32x4 acc[4][4];
#pragma unroll
    for (int i = 0; i < 4; i++)
#pragma unroll
        for (int j = 0; j < 4; j++) acc[i][j] = {0.f, 0.f, 0.f, 0.f};

    for (int kt = 0; kt < 20; kt++) {
        int k0 = kt * 32;
        int ct = (k0 >= RES) ? 1 : 0;
        int kk = k0 - RES * ct;
#pragma unroll
        for (int r = 0; r < 2; r++) {
            int c = r * 256 + tid;
            int row = c >> 2, koff = (c & 3) * 8;
            int gr = r0 + row;
            unsigned bb = (unsigned)gr / 320u;
            int m = gr - (int)bb * 320;
            GLD16(C1 + (size_t)(m + RES * ct) * NCOLS + bb * RES + kk + koff,
                  At + (size_t)(r * 256 + wave * 64) * 8);
            GLD16(F1 + (size_t)(n0 + row) * MDIM + k0 + koff,
                  Bt + (size_t)(r * 256 + wave * 64) * 8);
        }
        __syncthreads();
        short8 a[4], bf[4];
#pragma unroll
        for (int i = 0; i < 4; i++)
            a[i] = *(const short8*)&At[(wr * 64 + i * 16 + tl) * 32 + q * 8];
#pragma unroll
        for (int j = 0; j < 4; j++)
            bf[j] = *(const short8*)&Bt[(wc * 64 + j * 16 + tl) * 32 + q * 8];
#pragma unroll
        for (int i = 0; i < 4; i++)
#pragma unroll
            for (int j = 0; j < 4; j++)
                acc[i][j] = __builtin_amdgcn_mfma_f32_16x16x32_bf16(a[i], bf[j], acc[i][j], 0, 0, 0);
        __syncthreads();
    }
#pragma unroll
    for (int i = 0; i < 4; i++)
#pragma unroll
        for (int j = 0; j < 4; j++) {
            int npcol = n0 + wc * 64 + j * 16 + tl;
            int comp = npcol >= RES;
            int n = npcol - RES * comp;
#pragma unroll
            for (int t = 0; t < 4; t++) {
                int gr = r0 + wr * 64 + i * 16 + q * 4 + t;
                unsigned bb = (unsigned)gr / 320u;
                int m = gr - (int)bb * 320;
                float g = g00[2 * bb + comp];
                float sgn = ((m + n) & 1) ? -1.0f : 1.0f;
                out[(((size_t)bb * 2 + comp) * RES + m) * RES + n] = acc[i][j][t] + sgn * g;
            }
        }
}

extern "C" void kernel_launch(void* const* d_in, const int* in_sizes, int n_in,
                              void* d_out, int out_size, void* d_ws, size_t ws_size,
                              hipStream_t stream) {
    const float* ksp = (const float*)d_in[0];
    const float* traj = (const float*)d_in[1];

    // Workspace: M9 (9*CELLS f32) | M9s (9*CELLS f32) | F1 (640*640 bf16)
    //            | B1t (10240*640 bf16) | C1 (10240*640 bf16) | g00 (32 float2)
    float* ws = (float*)d_ws;
    float* M9 = ws;
    float* M9s = ws + (size_t)9 * CELLS;
    short* F1 = (short*)(ws + (size_t)18 * CELLS);
    short* B1t = F1 + (size_t)MDIM * MDIM;
    short* C1 = B1t + (size_t)NCOLS * MDIM;
    float* g00 = (float*)(C1 + (size_t)NCOLS * MDIM);

    hipMemsetAsync(M9, 0, (size_t)18 * CELLS * sizeof(float), stream);
    build_m9<<<RES / NJ, 320, 0, stream>>>(traj, M9, M9s);
    make_F1<<<(MDIM * MDIM + 255) / 256, 256, 0, stream>>>(F1);
    merge_m9<<<(9 * CELLS + 255) / 256, 256, 0, stream>>>(M9, M9s);
    stencil_t<<<dim3(10, 10, 32), 256, 0, stream>>>((const float2*)ksp, M9, B1t, g00);
    gemm1<<<dim3(80, 5), 256, 0, stream>>>(F1, B1t, C1);
    gemm2<<<dim3(5, 80), 256, 0, stream>>>(C1, F1, g00, (float*)d_out);
}

// Round 5
// 158.165 us; speedup vs baseline: 2.6468x; 1.0804x over previous
//
#include <hip/hip_runtime.h>

#define RES 320
#define CELLS (RES * RES)
#define MDIM 640      // 2*RES (Re/Im stacked)
#define NCOLS 10240   // 32 batches * RES

typedef __attribute__((ext_vector_type(8))) short short8;
typedef __attribute__((ext_vector_type(4))) float f32x4;

// round-to-nearest-even f32 -> bf16 bits (all values finite here)
static __device__ __forceinline__ short f2bf(float f) {
    unsigned u = __builtin_bit_cast(unsigned, f);
    unsigned r = (u + 0x7fffu + ((u >> 16) & 1u)) >> 16;
    return (short)r;
}

#define GLD16(g, l) __builtin_amdgcn_global_load_lds(                        \
    (const __attribute__((address_space(1))) void*)(g),                      \
    (__attribute__((address_space(3))) void*)(l), 16, 0, 0)

// ---------------------------------------------------------------------------
// Wave-level run-segmented atomic add: combines contiguous equal-key runs,
// one atomic per run (key < 0 => no atomic). Called once per thread at the
// end of build_m9 for the (rare) spill contributions; degenerate lanes are
// contiguous and share a key -> 1 atomic per wave.
// ---------------------------------------------------------------------------
__device__ __forceinline__ void seg_atomic_add(float* base, int key, float val, int lane) {
    int prev = __shfl_up(key, 1);
    bool head = (lane == 0) || (prev != key);
    unsigned long long hb = __ballot(head);
    unsigned long long below = (lane == 63) ? hb : (hb & ((1ULL << (lane + 1)) - 1ULL));
    int run_start = 63 - __clzll(below);
#pragma unroll
    for (int d = 1; d < 64; d <<= 1) {
        float o = __shfl_up(val, d);
        if (lane - d >= run_start) val += o;
    }
    bool tail = (lane == 63) || ((hb >> (lane + 1)) & 1ULL);
    if (tail && key >= 0) atomicAdd(base + key, val);
}

// ---------------------------------------------------------------------------
// Build M9, banded NJ=1 + halo planes. Band j (320 blocks): points with J=j,
// thread tid = I. In-bounds targets have cy in {j-1, j} -> LDS window
// acc[9][2][320]; lanes = consecutive I = consecutive cx = conflict-free
// ds_add. Flush: BOTH window rows go to per-band halo planes via plain
// float4 stores (no atomics): hal0[j] = row cy=j-1, hal1[j] = row cy=j.
// merge_m9 composes M9[cy] = hal1[cy] + hal0[cy+1] + spill. Out-of-window
// contributions (degenerate points -> cell 0) accumulate in one lazy
// register pair, flushed via seg_atomic into spill plane M9s.
// ---------------------------------------------------------------------------
__global__ __launch_bounds__(320) void build_m9(const float* __restrict__ traj,
                                                float* __restrict__ hal0,
                                                float* __restrict__ hal1,
                                                float* __restrict__ M9s) {
    __shared__ float acc[9 * 2 * RES];
    int j = blockIdx.x;     // band = J row
    int tid = threadIdx.x;  // = I
    int lane = tid & 63;
    for (int i = tid; i < 9 * 2 * RES; i += 320) acc[i] = 0.f;
    __syncthreads();

    const float2 t = ((const float2*)traj)[(size_t)tid * RES + j];
    float x = ((t.x * (2.0f / RES) + 1.0f) * RES - 1.0f) * 0.5f;
    float y = ((t.y * (2.0f / RES) + 1.0f) * RES - 1.0f) * 0.5f;
    float x0f = floorf(x), y0f = floorf(y);
    float fx = x - x0f, fy = y - y0f;
    int x0 = (int)x0f, y0 = (int)y0f;

    const int ox[4] = {0, 1, 0, 1};
    const int oy[4] = {0, 0, 1, 1};
    float w[4] = {(1.f - fx) * (1.f - fy), fx * (1.f - fy), (1.f - fx) * fy, fx * fy};
    int cxv[4], cyv[4];
    bool v[4];
#pragma unroll
    for (int k = 0; k < 4; k++) {
        int cx = x0 + ox[k], cy = y0 + oy[k];
        v[k] = (cx >= 0) && (cx < RES) && (cy >= 0) && (cy < RES);
        cxv[k] = cx;
        cyv[k] = cy;
    }
    int gkey = -1;
    float gval = 0.f;
#pragma unroll
    for (int jc = 0; jc < 4; jc++) {
#pragma unroll
        for (int ic = 0; ic < 4; ic++) {
            int slot = (oy[ic] - oy[jc] + 1) * 3 + (ox[ic] - ox[jc] + 1);
            bool valid = v[ic] && v[jc];
            float wv = w[jc] * w[ic];
            int wr = cyv[jc] - j + 1;  // in-window row if 0 or 1
            if (valid && ((unsigned)wr < 2u)) {
                atomicAdd(&acc[(slot * 2 + wr) * RES + cxv[jc]], wv);
            } else if (valid) {
                int g = slot * CELLS + cyv[jc] * RES + cxv[jc];
                if (g == gkey) {
                    gval += wv;
                } else {
                    if (gkey >= 0) atomicAdd(M9s + gkey, gval);
                    gkey = g;
                    gval = wv;
                }
            }
        }
    }
    seg_atomic_add(M9s, gkey, gval, lane);
    __syncthreads();
    // Flush both window rows to halo planes: plain float4 stores (full rows,
    // including zeros -> halos need no pre-zeroing).
    for (int i = tid; i < 9 * 2 * (RES / 4); i += 320) {
        int q = i % (RES / 4);
        int sr = i / (RES / 4);   // 0..17
        int wrow = sr & 1;
        int slot = sr >> 1;
        float4 v4 = *(const float4*)&acc[(slot * 2 + wrow) * RES + q * 4];
        float* hal = wrow ? hal1 : hal0;
        *(float4*)&hal[((size_t)j * 9 + slot) * RES + q * 4] = v4;
    }
}

// ---------------------------------------------------------------------------
// Compose M9[slot][cy][x] = hal1[cy] + hal0[cy+1] + M9s (spill).
// ---------------------------------------------------------------------------
__global__ __launch_bounds__(256) void merge_m9(float* __restrict__ M9,
                                                const float* __restrict__ hal0,
                                                const float* __restrict__ hal1,
                                                const float* __restrict__ M9s) {
    int i = blockIdx.x * 256 + threadIdx.x;
    if (i >= 9 * CELLS) return;
    int slot = i / CELLS;
    int rem = i - slot * CELLS;
    int cy = rem / RES;
    int x = rem - cy * RES;
    float s = hal1[((size_t)cy * 9 + slot) * RES + x] + M9s[i];
    if (cy + 1 < RES) s += hal0[((size_t)(cy + 1) * 9 + slot) * RES + x];
    M9[i] = s;
}

// ---------------------------------------------------------------------------
// F1[m'][y'] bf16, 640x640: block matrix [[Fr,-Fi],[Fi,Fr]] of
// F[u,y] = (-1)^(u+y) exp(+2*pi*i*u*y/RES). Also zeroes the spill plane M9s
// (fused to drop one dispatch). Must run BEFORE build_m9.
// ---------------------------------------------------------------------------
__global__ __launch_bounds__(256) void make_F1_zero(short* __restrict__ F1,
                                                    float* __restrict__ M9s) {
    int idx = blockIdx.x * 256 + threadIdx.x;
    if (idx < MDIM * MDIM) {
        int mp = idx / MDIM, yp = idx % MDIM;
        int cm = mp >= RES, cy = yp >= RES;
        int m = mp - RES * cm, y = yp - RES * cy;
        int r = (m * y) % RES;
        float s, c;
        sincospif((float)r * (2.0f / RES), &s, &c);
        float sign = ((m + y) & 1) ? -1.0f : 1.0f;
        float fr = sign * c, fi = sign * s;
        float val = (cm == 0) ? (cy == 0 ? fr : -fi) : (cy == 0 ? fi : fr);
        F1[idx] = f2bf(val);
    }
    if (idx < 9 * CELLS) M9s[idx] = 0.f;
}

// ---------------------------------------------------------------------------
// Stencil + transpose: grid'[b][y][x] = sum_s M9[s][y,x] * c[b][y+dy][x+dx],
// cell (0,0) extracted to g00[b] (exact fp32 rank-1 path) and zeroed.
// Output B1t[(b*320+x)][y'] bf16 (k-contiguous for stage-1 B-frags).
// ---------------------------------------------------------------------------
__global__ __launch_bounds__(256) void stencil_t(const float2* __restrict__ ksp,
                                                 const float* __restrict__ M9,
                                                 short* __restrict__ B1t,
                                                 float* __restrict__ g00) {
    __shared__ float2 Ls[32][33];
    int b = blockIdx.z;
    int tx0 = blockIdx.x * 32, ty0 = blockIdx.y * 32;
    int tid = threadIdx.x;
    int xl = tid & 31, yq = tid >> 5;
    const float2* kb = ksp + (size_t)b * CELLS;
#pragma unroll
    for (int rr = 0; rr < 4; rr++) {
        int yl = yq + 8 * rr;
        int y = ty0 + yl, x = tx0 + xl;
        int cell = y * RES + x;
        float re = 0.f, im = 0.f;
#pragma unroll
        for (int s = 0; s < 9; s++) {
            float w = M9[s * CELLS + cell];
            int dy = s / 3 - 1, dx = s % 3 - 1;
            int yn = min(max(y + dy, 0), RES - 1);
            int xn = min(max(x + dx, 0), RES - 1);
            float2 v = kb[yn * RES + xn];
            re = fmaf(w, v.x, re);
            im = fmaf(w, v.y, im);
        }
        if (cell == 0) {
            g00[2 * b] = re;
            g00[2 * b + 1] = im;
            re = 0.f;
            im = 0.f;
        }
        Ls[yl][xl] = make_float2(re, im);
    }
    __syncthreads();
    int xc = tid >> 3, yg = tid & 7;
    float2 v0 = Ls[yg * 4 + 0][xc], v1 = Ls[yg * 4 + 1][xc];
    float2 v2 = Ls[yg * 4 + 2][xc], v3 = Ls[yg * 4 + 3][xc];
    uint2 pr, pi;
    pr.x = (unsigned short)f2bf(v0.x) | ((unsigned)(unsigned short)f2bf(v1.x) << 16);
    pr.y = (unsigned short)f2bf(v2.x) | ((unsigned)(unsigned short)f2bf(v3.x) << 16);
    pi.x = (unsigned short)f2bf(v0.y) | ((unsigned)(unsigned short)f2bf(v1.y) << 16);
    pi.y = (unsigned short)f2bf(v2.y) | ((unsigned)(unsigned short)f2bf(v3.y) << 16);
    size_t rowbase = ((size_t)b * RES + tx0 + xc) * MDIM;
    *(uint2*)(B1t + rowbase + ty0 + yg * 4) = pr;
    *(uint2*)(B1t + rowbase + RES + ty0 + yg * 4) = pi;
}

// ---------------------------------------------------------------------------
// Stage 1: C1[m'][(b,x)] = sum_y' F1[m'][y'] * B1t[(b,x)][y']
// M=640, N=10240, K=640. 64x128 tile (800 blocks for CU balance), BK=32,
// 4 waves, each 32x64 via 2x4 16x16x32 MFMA frags.
// ---------------------------------------------------------------------------
__global__ __launch_bounds__(256) void gemm1(const short* __restrict__ F1,
                                             const short* __restrict__ B1t,
                                             short* __restrict__ C1) {
    __shared__ short At[64 * 32];
    __shared__ short Bt[128 * 32];
    int tid = threadIdx.x;
    int lane = tid & 63, wave = tid >> 6;
    int wr = wave >> 1, wc = wave & 1;
    int m0 = blockIdx.y * 64, n0 = blockIdx.x * 128;
    int q = lane >> 4, tl = lane & 15;
    f32x4 acc[2][4];
#pragma unroll
    for (int i = 0; i < 2; i++)
#pragma unroll
        for (int j = 0; j < 4; j++) acc[i][j] = {0.f, 0.f, 0.f, 0.f};

    for (int kt = 0; kt < 20; kt++) {
        int k0 = kt * 32;
        {
            int row = tid >> 2, koff = (tid & 3) * 8;
            GLD16(F1 + (size_t)(m0 + row) * MDIM + k0 + koff,
                  At + (size_t)(wave * 64) * 8);
        }
#pragma unroll
        for (int r = 0; r < 2; r++) {
            int c = r * 256 + tid;
            int row = c >> 2, koff = (c & 3) * 8;
            GLD16(B1t + (size_t)(n0 + row) * MDIM + k0 + koff,
                  Bt + (size_t)(r * 256 + wave * 64) * 8);
        }
        __syncthreads();
        short8 a[2], bf[4];
#pragma unroll
        for (int i = 0; i < 2; i++)
            a[i] = *(const short8*)&At[(wr * 32 + i * 16 + tl) * 32 + q * 8];
#pragma unroll
        for (int j = 0; j < 4; j++)
            bf[j] = *(const short8*)&Bt[(wc * 64 + j * 16 + tl) * 32 + q * 8];
#pragma unroll
        for (int i = 0; i < 2; i++)
#pragma unroll
            for (int j = 0; j < 4; j++)
                acc[i][j] = __builtin_amdgcn_mfma_f32_16x16x32_bf16(a[i], bf[j], acc[i][j], 0, 0, 0);
        __syncthreads();
    }
#pragma unroll
    for (int i = 0; i < 2; i++)
#pragma unroll
        for (int j = 0; j < 4; j++)
#pragma unroll
            for (int t = 0; t < 4; t++) {
                int mrow = m0 + wr * 32 + i * 16 + q * 4 + t;
                int ncol = n0 + wc * 64 + j * 16 + tl;
                C1[(size_t)mrow * NCOLS + ncol] = f2bf(acc[i][j][t]);
            }
}

// ---------------------------------------------------------------------------
// Stage 2: out[(b,m)][n'] = sum_x' T2[(b,m)][x'] * F1[n'][x'], with
// T2[(b,m)][x+320*ct] = C1[m+320*ct][b*320+x]. 128x64 tile (800 blocks),
// 4 waves, each 64x32 via 4x2 frags. Epilogue adds the rank-1 checkerboard
// g00[b]*(-1)^(m+n) and writes planar out (b,1,2,H,W).
// ---------------------------------------------------------------------------
__global__ __launch_bounds__(256) void gemm2(const short* __restrict__ C1,
                                             const short* __restrict__ F1,
                                             const float* __restrict__ g00,
                                             float* __restrict__ out) {
    __shared__ short At[128 * 32];
    __shared__ short Bt[64 * 32];
    int tid = threadIdx.x;
    int lane = tid & 63, wave = tid >> 6;
    int wr = wave >> 1, wc = wave & 1;
    int r0 = blockIdx.y * 128, n0 = blockIdx.x * 64;
    int q = lane >> 4, tl = lane & 15;
    f32x4 acc[4][2];
#pragma unroll
    for (int i = 0; i < 4; i++)
#pragma unroll
        for (int j = 0; j < 2; j++) acc[i][j] = {0.f, 0.f, 0.f, 0.f};

    for (int kt = 0; kt < 20; kt++) {
        int k0 = kt * 32;
        int ct = (k0 >= RES) ? 1 : 0;
        int kk = k0 - RES * ct;
#pragma unroll
        for (int r = 0; r < 2; r++) {
            int c = r * 256 + tid;
            int row = c >> 2, koff = (c & 3) * 8;
            int gr = r0 + row;
            unsigned bb = (unsigned)gr / 320u;
            int m = gr - (int)bb * 320;
            GLD16(C1 + (size_t)(m + RES * ct) * NCOLS + bb * RES + kk + koff,
                  At + (size_t)(r * 256 + wave * 64) * 8);
        }
        {
            int row = tid >> 2, koff = (tid & 3) * 8;
            GLD16(F1 + (size_t)(n0 + row) * MDIM + k0 + koff,
                  Bt + (size_t)(wave * 64) * 8);
        }
        __syncthreads();
        short8 a[4], bf[2];
#pragma unroll
        for (int i = 0; i < 4; i++)
            a[i] = *(const short8*)&At[(wr * 64 + i * 16 + tl) * 32 + q * 8];
#pragma unroll
        for (int j = 0; j < 2; j++)
            bf[j] = *(const short8*)&Bt[(wc * 32 + j * 16 + tl) * 32 + q * 8];
#pragma unroll
        for (int i = 0; i < 4; i++)
#pragma unroll
            for (int j = 0; j < 2; j++)
                acc[i][j] = __builtin_amdgcn_mfma_f32_16x16x32_bf16(a[i], bf[j], acc[i][j], 0, 0, 0);
        __syncthreads();
    }
#pragma unroll
    for (int i = 0; i < 4; i++)
#pragma unroll
        for (int j = 0; j < 2; j++) {
            int npcol = n0 + wc * 32 + j * 16 + tl;
            int comp = npcol >= RES;
            int n = npcol - RES * comp;
#pragma unroll
            for (int t = 0; t < 4; t++) {
                int gr = r0 + wr * 64 + i * 16 + q * 4 + t;
                unsigned bb = (unsigned)gr / 320u;
                int m = gr - (int)bb * 320;
                float g = g00[2 * bb + comp];
                float sgn = ((m + n) & 1) ? -1.0f : 1.0f;
                out[(((size_t)bb * 2 + comp) * RES + m) * RES + n] = acc[i][j][t] + sgn * g;
            }
        }
}

extern "C" void kernel_launch(void* const* d_in, const int* in_sizes, int n_in,
                              void* d_out, int out_size, void* d_ws, size_t ws_size,
                              hipStream_t stream) {
    const float* ksp = (const float*)d_in[0];
    const float* traj = (const float*)d_in[1];

    // Workspace (floats): M9 9*CELLS | M9s 9*CELLS | hal0 9*CELLS | hal1 9*CELLS
    //                     | F1 (bf16) | B1t (bf16) | C1 (bf16) | g00
    float* ws = (float*)d_ws;
    float* M9 = ws;
    float* M9s = ws + (size_t)9 * CELLS;
    float* hal0 = ws + (size_t)18 * CELLS;
    float* hal1 = ws + (size_t)27 * CELLS;
    short* F1 = (short*)(ws + (size_t)36 * CELLS);
    short* B1t = F1 + (size_t)MDIM * MDIM;
    short* C1 = B1t + (size_t)NCOLS * MDIM;
    float* g00 = (float*)(C1 + (size_t)NCOLS * MDIM);

    make_F1_zero<<<(9 * CELLS + 255) / 256, 256, 0, stream>>>(F1, M9s);
    build_m9<<<RES, 320, 0, stream>>>(traj, hal0, hal1, M9s);
    merge_m9<<<(9 * CELLS + 255) / 256, 256, 0, stream>>>(M9, hal0, hal1, M9s);
    stencil_t<<<dim3(10, 10, 32), 256, 0, stream>>>((const float2*)ksp, M9, B1t, g00);
    gemm1<<<dim3(80, 10), 256, 0, stream>>>(F1, B1t, C1);
    gemm2<<<dim3(10, 80), 256, 0, stream>>>(C1, F1, g00, (float*)d_out);
}